// Round 1
// baseline (427.389 us; speedup 1.0000x reference)
//
#include <hip/hip_runtime.h>
#include <math.h>

#define LN_EPS 1e-5f

// Problem constants: N=512, L=256, P=64
// ws layout (floats):
//   0       proj[4][512][128]  (lg, lv, rg, rv)
//   262144  left [512][128]
//   327680  right[512][128]
//   393216  A [512][64]
//   425984  B [512][64]
//   458752  C [512][512]
//   720896  sums: sumL[512] ssL[512] sumR[512] ssR[512]
//   722944  cs0[64] cs1[64]

__device__ __forceinline__ float gelu_f(float x) {
    // jax.nn.gelu approximate=True: 0.5x(1+tanh(sqrt(2/pi)(x+0.044715x^3)))
    float x3 = x * x * x;
    float t = 0.7978845608028654f * (x + 0.044715f * x3);
    float e = __expf(2.f * t);          // inf-safe: e->inf => tanh->1; e->0 => tanh->-1
    float th = 1.f - 2.f / (e + 1.f);
    return 0.5f * x * (1.f + th);
}

// ---------------- Kernel A: l = LN(local); lg/lv/rg/rv = l @ W_* ----------------
__global__ void kA(const float* __restrict__ loc,
                   const float* __restrict__ Wlg, const float* __restrict__ Wlv,
                   const float* __restrict__ Wrg, const float* __restrict__ Wrv,
                   float* __restrict__ proj) {
    const int t = threadIdx.x;
    const int i = blockIdx.x;
    __shared__ float ln_sh[256];
    __shared__ float stats[2];
    if (t < 64) {
        float4 v = ((const float4*)(loc + i * 256))[t];
        float s = v.x + v.y + v.z + v.w;
        float ss = v.x * v.x + v.y * v.y + v.z * v.z + v.w * v.w;
#pragma unroll
        for (int off = 1; off < 64; off <<= 1) {
            s += __shfl_xor(s, off);
            ss += __shfl_xor(ss, off);
        }
        if (t == 0) {
            float mu = s * (1.f / 256.f);
            float var = ss * (1.f / 256.f) - mu * mu;
            stats[0] = mu;
            stats[1] = rsqrtf(var + LN_EPS);
        }
    }
    __syncthreads();
    float mu = stats[0], rs = stats[1];
    ln_sh[t] = (loc[i * 256 + t] - mu) * rs;
    __syncthreads();
#pragma unroll
    for (int h = 0; h < 2; ++h) {
        int o = t + h * 256;
        int mat = o >> 7, n = o & 127;
        const float* W = (mat == 0) ? Wlg : (mat == 1) ? Wlv : (mat == 2) ? Wrg : Wrv;
        float acc = 0.f;
#pragma unroll 8
        for (int k = 0; k < 256; ++k) acc += ln_sh[k] * W[k * 128 + n];
        proj[mat * 65536 + i * 128 + n] = acc;
    }
}

// ---------------- Kernel B: fused p-LN + dual GEMM + gelu-gate + dual reduction ----------------
// grid (32,16): 16 i's x 32 j's per block. 256 threads = 2 j-groups x 128 n.
// Weight columns live in 128 VGPRs per thread; LN folded via column sums.
__global__ __launch_bounds__(256, 2)
void kB(const float* __restrict__ pair, const int* __restrict__ mask,
        const float* __restrict__ Wg, const float* __restrict__ Wv,
        const float* __restrict__ lg, const float* __restrict__ lv,
        const float* __restrict__ rg, const float* __restrict__ rv,
        float* __restrict__ left, float* __restrict__ right) {
    const int TI = 16, TJ = 32;
    __shared__ float x_sh[TJ][64];
    __shared__ float mu_sh[TJ], rs_sh[TJ];
    __shared__ float lv_sh[TJ][128];
    __shared__ float rg_sh[TJ][128];
    __shared__ float racc[TJ][128];
    __shared__ int mask_sh[TJ];

    const int t = threadIdx.x;
    const int n = t & 127;
    const int jg = t >> 7;
    const int i0 = blockIdx.x * TI;
    const int j0 = blockIdx.y * TJ;

    float wg[64], wv[64];
    float csg = 0.f, csv = 0.f;
#pragma unroll
    for (int k = 0; k < 64; ++k) {
        wg[k] = Wg[k * 128 + n]; csg += wg[k];
        wv[k] = Wv[k * 128 + n]; csv += wv[k];
    }
    for (int idx = t; idx < TJ * 128; idx += 256) {
        int jj = idx >> 7, nn = idx & 127;
        lv_sh[jj][nn] = lv[(j0 + jj) * 128 + nn];
        rg_sh[jj][nn] = rg[(j0 + jj) * 128 + nn];
        racc[jj][nn] = 0.f;
    }
    if (t < TJ) mask_sh[t] = mask[j0 + t];
    __syncthreads();

    for (int ii = 0; ii < TI; ++ii) {
        const int i = i0 + ii;
        __syncthreads();  // protect x_sh from previous iteration's readers
        {   // stage pair[i, j0:j0+32, :] = 2048 floats
            const float4* src = (const float4*)(pair + ((size_t)i * 512 + j0) * 64);
            float4 v0 = src[t];
            float4 v1 = src[t + 256];
            ((float4*)&x_sh[0][0])[t] = v0;
            ((float4*)&x_sh[0][0])[t + 256] = v1;
        }
        __syncthreads();
        {   // per-row LN stats: 8 threads per row
            int row = t >> 3, sub = t & 7;
            float s = 0.f, ss = 0.f;
#pragma unroll
            for (int u = 0; u < 8; ++u) {
                float v = x_sh[row][sub * 8 + u];
                s += v; ss += v * v;
            }
            s += __shfl_xor(s, 1); ss += __shfl_xor(ss, 1);
            s += __shfl_xor(s, 2); ss += __shfl_xor(ss, 2);
            s += __shfl_xor(s, 4); ss += __shfl_xor(ss, 4);
            if (sub == 0) {
                float mu = s * (1.f / 64.f);
                float var = ss * (1.f / 64.f) - mu * mu;
                mu_sh[row] = mu;
                rs_sh[row] = rsqrtf(var + LN_EPS);
            }
        }
        __syncthreads();

        const float lgi = lg[i * 128 + n];
        const float rvi = rv[i * 128 + n];
        const int mi = mask[i];
        float lreg = 0.f;

        for (int jj = 0; jj < TJ; jj += 2) {
            const int j = jj + jg;  // wave-uniform
            const float mu = mu_sh[j], rs = rs_sh[j];
            float rawg = 0.f, rawv = 0.f;
#pragma unroll
            for (int k = 0; k < 64; ++k) {
                float xv = x_sh[j][k];
                rawg += xv * wg[k];
                rawv += xv * wv[k];
            }
            float pg = rs * (rawg - mu * csg);
            float pv = rs * (rawv - mu * csv);
            float coef = (mi && mask_sh[j]) ? 1.f : 0.f;
            float lc = gelu_f(lgi + pg) * (lv_sh[j][n] + pv);
            lreg += coef * lc;
            float rc = gelu_f(rg_sh[j][n] + pg) * (rvi + pv);
            racc[j][n] += coef * rc;  // single writer per (j,n)
        }
        atomicAdd(&left[i * 128 + n], lreg);
    }
    __syncthreads();
    for (int idx = t; idx < TJ * 128; idx += 256) {
        int jj = idx >> 7, nn = idx & 127;
        atomicAdd(&right[(j0 + jj) * 128 + nn], racc[jj][nn]);
    }
}

// ---------------- Kernel D1: row sums/sumsq of left/right, A/B = row @ W_out[64:], colsums ----------------
__global__ void kD1(const float* __restrict__ left, const float* __restrict__ right,
                    const float* __restrict__ W_out,
                    float* __restrict__ Aw, float* __restrict__ Bw,
                    float* __restrict__ sums, float* __restrict__ cs) {
    const int t = threadIdx.x;
    const int r = blockIdx.x;
    const int which = blockIdx.y;
    const float* src = which ? right : left;
    __shared__ float row_sh[128];
    __shared__ float red[4];
    float v = src[r * 128 + t];
    row_sh[t] = v;
    float s = v, ss = v * v;
#pragma unroll
    for (int off = 1; off < 64; off <<= 1) {
        s += __shfl_xor(s, off);
        ss += __shfl_xor(ss, off);
    }
    int wid = t >> 6, lane = t & 63;
    if (lane == 0) { red[wid * 2] = s; red[wid * 2 + 1] = ss; }
    __syncthreads();
    if (t == 0) {
        sums[which * 1024 + r] = red[0] + red[2];
        sums[which * 1024 + 512 + r] = red[1] + red[3];
    }
    if (t < 64) {
        float a = 0.f;
        const float* W2 = W_out + 64 * 64;
#pragma unroll 8
        for (int m = 0; m < 128; ++m) a += row_sh[m] * W2[m * 64 + t];
        (which ? Bw : Aw)[r * 64 + t] = a;
    }
    if (r == 0 && which == 0 && t < 64) {
        float c0 = 0.f, c1 = 0.f;
        for (int k = 0; k < 64; ++k) c0 += W_out[k * 64 + t];
        for (int m = 0; m < 128; ++m) c1 += W_out[(64 + m) * 64 + t];
        cs[t] = c0;
        cs[64 + t] = c1;
    }
}

// ---------------- Kernel D2: C = left @ right^T  (512x512, K=128) ----------------
__global__ void kD2(const float* __restrict__ left, const float* __restrict__ right,
                    float* __restrict__ C) {
    __shared__ float l_sh[32][68];
    __shared__ float r_sh[32][68];
    const int t = threadIdx.x;
    const int tx = t & 15, ty = t >> 4;
    const int i0 = blockIdx.x * 32, j0 = blockIdx.y * 32;
    float acc00 = 0.f, acc01 = 0.f, acc10 = 0.f, acc11 = 0.f;
    for (int kc = 0; kc < 128; kc += 64) {
        __syncthreads();
#pragma unroll
        for (int u = 0; u < 2; ++u) {
            int fi = t + u * 256;  // 0..511: row = fi>>4, 16 float4 per row
            int row = fi >> 4, kq = (fi & 15) * 4;
            float4 lv4 = *(const float4*)(left + (i0 + row) * 128 + kc + kq);
            float4 rv4 = *(const float4*)(right + (j0 + row) * 128 + kc + kq);
            *(float4*)&l_sh[row][kq] = lv4;
            *(float4*)&r_sh[row][kq] = rv4;
        }
        __syncthreads();
#pragma unroll 8
        for (int k = 0; k < 64; ++k) {
            float l0 = l_sh[ty * 2 + 0][k], l1 = l_sh[ty * 2 + 1][k];
            float r0 = r_sh[tx * 2 + 0][k], r1 = r_sh[tx * 2 + 1][k];
            acc00 += l0 * r0; acc01 += l0 * r1;
            acc10 += l1 * r0; acc11 += l1 * r1;
        }
    }
    C[(size_t)(i0 + ty * 2 + 0) * 512 + j0 + tx * 2 + 0] = acc00;
    C[(size_t)(i0 + ty * 2 + 0) * 512 + j0 + tx * 2 + 1] = acc01;
    C[(size_t)(i0 + ty * 2 + 1) * 512 + j0 + tx * 2 + 0] = acc10;
    C[(size_t)(i0 + ty * 2 + 1) * 512 + j0 + tx * 2 + 1] = acc11;
}

// ---------------- Kernel C: out = rs_p*(x@Wo0 - mu_p*cs0) + rs_s*(A[i]+B[j] - mu_s*cs1) ----------------
// grid (512, 8): one i-row x 64 j's per block. 256 threads = 4 j-groups (one wave each) x 64 n.
__global__ void kC(const float* __restrict__ pair,
                   const float* __restrict__ W_out,
                   const float* __restrict__ Aw, const float* __restrict__ Bw,
                   const float* __restrict__ Cw, const float* __restrict__ sums,
                   const float* __restrict__ cs, float* __restrict__ out) {
    __shared__ float x_sh[4][64];  // one private row per wave -> no barriers needed
    const int t = threadIdx.x;
    const int n = t & 63;
    const int jg = t >> 6;
    const int i = blockIdx.x;
    const int j0 = blockIdx.y * 64;

    float wo_r[64];
#pragma unroll
    for (int k = 0; k < 64; ++k) wo_r[k] = W_out[k * 64 + n];

    const float A_in = Aw[i * 64 + n];
    const float sumLi = sums[i], ssLi = sums[512 + i];
    const float cs0n = cs[n], cs1n = cs[64 + n];

    for (int jj4 = 0; jj4 < 16; ++jj4) {
        const int j = j0 + jj4 * 4 + jg;  // wave-uniform
        const size_t base = ((size_t)i * 512 + j) * 64;
        float xv = pair[base + n];
        x_sh[jg][n] = xv;
        float s = xv, ss = xv * xv;
#pragma unroll
        for (int off = 1; off < 64; off <<= 1) {
            s += __shfl_xor(s, off);
            ss += __shfl_xor(ss, off);
        }
        float mu_p = s * (1.f / 64.f);
        float rs_p = rsqrtf(ss * (1.f / 64.f) - mu_p * mu_p + LN_EPS);
        float raw = 0.f;
#pragma unroll
        for (int k = 0; k < 64; ++k) raw += x_sh[jg][k] * wo_r[k];
        float Bv = Bw[j * 64 + n];
        float sumRj = sums[1024 + j], ssRj = sums[1536 + j];
        float Cv = Cw[(size_t)i * 512 + j];
        float mu_s = (sumLi + sumRj) * (1.f / 128.f);
        float var_s = (ssLi + 2.f * Cv + ssRj) * (1.f / 128.f) - mu_s * mu_s;
        float rs_s = rsqrtf(var_s + LN_EPS);
        out[base + n] = rs_p * (raw - mu_p * cs0n) + rs_s * (A_in + Bv - mu_s * cs1n);
    }
}

extern "C" void kernel_launch(void* const* d_in, const int* in_sizes, int n_in,
                              void* d_out, int out_size, void* d_ws, size_t ws_size,
                              hipStream_t stream) {
    const float* loc  = (const float*)d_in[0];
    const float* pair = (const float*)d_in[1];
    const int*   mask = (const int*)d_in[2];
    const float* Wpg  = (const float*)d_in[3];
    const float* Wpv  = (const float*)d_in[4];
    const float* Wlg  = (const float*)d_in[5];
    const float* Wlv  = (const float*)d_in[6];
    const float* Wrg  = (const float*)d_in[7];
    const float* Wrv  = (const float*)d_in[8];
    const float* Wout = (const float*)d_in[9];
    float* out = (float*)d_out;
    float* ws = (float*)d_ws;

    float* proj  = ws;             // 4 * 512*128
    float* left  = ws + 262144;    // 512*128
    float* right = ws + 327680;    // 512*128
    float* Aw    = ws + 393216;    // 512*64
    float* Bw    = ws + 425984;    // 512*64
    float* Cw    = ws + 458752;    // 512*512
    float* sums  = ws + 720896;    // 2048
    float* cs    = ws + 722944;    // 128

    hipMemsetAsync(left, 0, 2 * 65536 * sizeof(float), stream);  // left+right

    kA<<<512, 256, 0, stream>>>(loc, Wlg, Wlv, Wrg, Wrv, proj);
    kB<<<dim3(32, 16), 256, 0, stream>>>(pair, mask, Wpg, Wpv,
                                         proj, proj + 65536, proj + 131072, proj + 196608,
                                         left, right);
    kD1<<<dim3(512, 2), 128, 0, stream>>>(left, right, Wout, Aw, Bw, sums, cs);
    kD2<<<dim3(16, 16), 256, 0, stream>>>(left, right, Cw);
    kC<<<dim3(512, 8), 256, 0, stream>>>(pair, Wout, Aw, Bw, Cw, sums, cs, out);
}